// Round 5
// baseline (398.656 us; speedup 1.0000x reference)
//
#include <hip/hip_runtime.h>

// Problem constants
#define Bb 256
#define Kk 256
#define NCLS 10

typedef __attribute__((ext_vector_type(8))) short short8;
typedef __attribute__((ext_vector_type(4))) float f32x4;

__device__ __forceinline__ float bf2f(ushort u) {
    return __uint_as_float(((unsigned int)u) << 16);
}
__device__ __forceinline__ ushort f2bf(float f) {
    unsigned int u = __float_as_uint(f);
    u = (u + 0x7FFFu + ((u >> 16) & 1u)) >> 16;
    return (ushort)u;
}
__device__ __forceinline__ float tanh_fast(float v) {
    float t = __expf(2.f * v);
    return (t - 1.f) / (t + 1.f);
}

// ---------------------------------------------------------------------------
// Level GEMM. Output tile BM=128 x BN=128, BK=32, 4 waves (2x2), wave tile
// 64x64 = 4x4 frags of mfma_f32_16x16x32_bf16.
// MIN_: 0 = FIRST (A = tanh(x*Win), rank-1), 1 = NORM (A = p0*p1, bf16,
// already normalized), 2 = RAW (A = (p0*p1)/(c0*c1), fp32 unnormalized).
// RAWOUT: false -> normalize by own full-K colsum, store bf16 proj.
//         true  -> atomicAdd fp32 partials (P and colsum C); grid.z = K-split.
// ---------------------------------------------------------------------------
template<int MIN_, bool RAWOUT>
__global__ __launch_bounds__(256, 3)
void level_kernel(const float*  __restrict__ x,      // (B,256)        [MIN_=0]
                  const float*  __restrict__ Win,    // (256,256)      [MIN_=0]
                  const ushort* __restrict__ Pprev,  // (B,2n,2,K)bf16 [MIN_=1]
                  const float*  __restrict__ Rprev,  // (B,2n,2,K)f32  [MIN_=2]
                  const float*  __restrict__ Cprev,  // (2n,2,K)f32    [MIN_=2]
                  const float*  __restrict__ W,      // (n,2,K,K) f32
                  ushort*       __restrict__ Pout,   // (B,n,2,K) bf16 [!RAWOUT]
                  float*        __restrict__ Rout,   // (B,n,2,K) f32  [RAWOUT]
                  float*        __restrict__ Cout,   // (n,2,K)   f32  [RAWOUT]
                  int n, int kchunk)
{
    __shared__ __align__(16) ushort sA[128 * 40];
    __shared__ __align__(16) ushort sE[128 * 40];
    __shared__ float sRed[2][128];
    __shared__ float sRcp[128];

    const int tid = threadIdx.x;
    const int bh  = blockIdx.x & 1;
    const int jt  = (blockIdx.x >> 1) & 1;
    const int a   = blockIdx.x >> 2;
    const int i   = blockIdx.y;
    const int d   = 2 * i + a;
    const int b0  = bh * 128;
    const int j0  = jt * 128;
    const int np  = 2 * n;

    const int l   = tid & 63;
    const int l15 = l & 15;
    const int g   = l >> 4;
    const int w   = tid >> 6;
    const int wm  = w >> 1;
    const int wn  = w & 1;

    const int ej  = tid & 127;
    const int ekq = tid >> 7;

    f32x4 acc[4][4];
    #pragma unroll
    for (int mf = 0; mf < 4; ++mf)
        #pragma unroll
        for (int nf = 0; nf < 4; ++nf)
            acc[mf][nf] = (f32x4){0.f, 0.f, 0.f, 0.f};

    float csum = 0.f;
    const size_t wbase = ((size_t)(i * 2 + a)) * (size_t)(Kk * Kk);
    const int kb = blockIdx.z * kchunk;

    for (int k0 = kb; k0 < kb + kchunk; k0 += 32) {
        // ---- stage A: 128 rows x 32 k bf16, 80B-padded rows ----
        #pragma unroll
        for (int p = 0; p < 2; ++p) {
            const int unit = p * 256 + tid;     // 0..511
            const int m = unit >> 2;            // 0..127
            const int s = unit & 3;             // 16B slice
            const int b = b0 + m;
            ushort pk[8];
            if (MIN_ == 0) {
                const float4 w0 = *(const float4*)&Win[(size_t)d * Kk + k0 + s * 8];
                const float4 w1 = *(const float4*)&Win[(size_t)d * Kk + k0 + s * 8 + 4];
                const float xv = x[(size_t)b * 256 + d];
                pk[0] = f2bf(tanh_fast(xv * w0.x));
                pk[1] = f2bf(tanh_fast(xv * w0.y));
                pk[2] = f2bf(tanh_fast(xv * w0.z));
                pk[3] = f2bf(tanh_fast(xv * w0.w));
                pk[4] = f2bf(tanh_fast(xv * w1.x));
                pk[5] = f2bf(tanh_fast(xv * w1.y));
                pk[6] = f2bf(tanh_fast(xv * w1.z));
                pk[7] = f2bf(tanh_fast(xv * w1.w));
            } else if (MIN_ == 1) {
                const size_t base = (((size_t)b * np + d) * 2) * 256 + k0 + s * 8;
                const short8 p0 = *(const short8*)&Pprev[base];
                const short8 p1 = *(const short8*)&Pprev[base + 256];
                #pragma unroll
                for (int e = 0; e < 8; ++e)
                    pk[e] = f2bf(bf2f((ushort)p0[e]) * bf2f((ushort)p1[e]));
            } else {
                const size_t base = (((size_t)b * np + d) * 2) * 256 + k0 + s * 8;
                const float4 p0a = *(const float4*)&Rprev[base];
                const float4 p0b = *(const float4*)&Rprev[base + 4];
                const float4 p1a = *(const float4*)&Rprev[base + 256];
                const float4 p1b = *(const float4*)&Rprev[base + 260];
                const size_t cb = (size_t)(d * 2) * 256 + k0 + s * 8;
                const float4 c0a = *(const float4*)&Cprev[cb];
                const float4 c0b = *(const float4*)&Cprev[cb + 4];
                const float4 c1a = *(const float4*)&Cprev[cb + 256];
                const float4 c1b = *(const float4*)&Cprev[cb + 260];
                const float p0r[8] = {p0a.x,p0a.y,p0a.z,p0a.w,p0b.x,p0b.y,p0b.z,p0b.w};
                const float p1r[8] = {p1a.x,p1a.y,p1a.z,p1a.w,p1b.x,p1b.y,p1b.z,p1b.w};
                const float c0r[8] = {c0a.x,c0a.y,c0a.z,c0a.w,c0b.x,c0b.y,c0b.z,c0b.w};
                const float c1r[8] = {c1a.x,c1a.y,c1a.z,c1a.w,c1b.x,c1b.y,c1b.z,c1b.w};
                #pragma unroll
                for (int e = 0; e < 8; ++e)
                    pk[e] = f2bf((p0r[e] * p1r[e]) / (c0r[e] * c1r[e]));
            }
            short8 v;
            #pragma unroll
            for (int e = 0; e < 8; ++e) v[e] = (short)pk[e];
            *(short8*)&sA[m * 40 + s * 8] = v;
        }

        // ---- stage E = exp(W) transposed to [j][k]; partial colsum ----
        #pragma unroll
        for (int h2 = 0; h2 < 2; ++h2) {
            const int kk = ekq * 16 + h2 * 8;
            ushort pk[8];
            #pragma unroll
            for (int r = 0; r < 8; ++r) {
                const float wv = W[wbase + (size_t)(k0 + kk + r) * 256 + j0 + ej];
                const float e = __expf(wv);
                csum += e;
                pk[r] = f2bf(e);
            }
            short8 v;
            #pragma unroll
            for (int e = 0; e < 8; ++e) v[e] = (short)pk[e];
            *(short8*)&sE[ej * 40 + kk] = v;
        }
        __syncthreads();

        // ---- MFMA: wave tile 64x64 = 4x4 frags ----
        short8 bfr[4];
        #pragma unroll
        for (int nf = 0; nf < 4; ++nf)
            bfr[nf] = *(const short8*)&sE[(wn * 64 + nf * 16 + l15) * 40 + g * 8];
        #pragma unroll
        for (int mf = 0; mf < 4; ++mf) {
            const short8 afr = *(const short8*)&sA[(wm * 64 + mf * 16 + l15) * 40 + g * 8];
            #pragma unroll
            for (int nf = 0; nf < 4; ++nf)
                acc[mf][nf] = __builtin_amdgcn_mfma_f32_16x16x32_bf16(
                    afr, bfr[nf], acc[mf][nf], 0, 0, 0);
        }
        __syncthreads();
    }

    // ---- colsum reduce over this block's K range ----
    sRed[ekq][ej] = csum;
    __syncthreads();
    if (!RAWOUT) {
        if (tid < 128) sRcp[tid] = 1.f / (sRed[0][tid] + sRed[1][tid]);
        __syncthreads();
    } else {
        if (tid < 128) {
            const float cpart = sRed[0][tid] + sRed[1][tid];
            atomicAdd(&Cout[(size_t)(i * 2 + a) * 256 + j0 + tid], cpart);
        }
    }

    // ---- epilogue ----
    if (!RAWOUT) {
        float rj[4];
        #pragma unroll
        for (int nf = 0; nf < 4; ++nf) rj[nf] = sRcp[wn * 64 + nf * 16 + l15];
        #pragma unroll
        for (int mf = 0; mf < 4; ++mf)
            #pragma unroll
            for (int nf = 0; nf < 4; ++nf) {
                const int jl = wn * 64 + nf * 16 + l15;
                #pragma unroll
                for (int r = 0; r < 4; ++r) {
                    const int b = b0 + wm * 64 + mf * 16 + g * 4 + r;
                    const size_t off = (((size_t)b * n + i) * 2 + a) * 256 + j0 + jl;
                    Pout[off] = f2bf(acc[mf][nf][r] * rj[nf]);
                }
            }
    } else {
        #pragma unroll
        for (int mf = 0; mf < 4; ++mf)
            #pragma unroll
            for (int nf = 0; nf < 4; ++nf) {
                const int jl = wn * 64 + nf * 16 + l15;
                #pragma unroll
                for (int r = 0; r < 4; ++r) {
                    const int b = b0 + wm * 64 + mf * 16 + g * 4 + r;
                    const size_t off = (((size_t)b * n + i) * 2 + a) * 256 + j0 + jl;
                    atomicAdd(&Rout[off], acc[mf][nf][r]);
                }
            }
    }
}

// Zero the fp32 atomic-accumulation region.
__global__ void zero_kernel(float4* __restrict__ p, int n4)
{
    int idx = blockIdx.x * blockDim.x + threadIdx.x;
    const int stride = gridDim.x * blockDim.x;
    for (; idx < n4; idx += stride) p[idx] = (float4){0.f, 0.f, 0.f, 0.f};
}

// Head: root[b,k] = (R7[b,0,0,k]/C7[0,0,k]) * (R7[b,0,1,k]/C7[0,1,k]);
// out[b,c] = sum_k root[b,k]*exp(Wout[k,c]) / colsum_c
__global__ __launch_bounds__(256)
void out_kernel(const float* __restrict__ R7,    // (B,1,2,K) f32 unnormalized
                const float* __restrict__ C7,    // (1,2,K) f32
                const float* __restrict__ Wout,  // (K, NCLS)
                float*       __restrict__ out)   // (B,1,NCLS)
{
    __shared__ float sR[16][260];
    __shared__ float sE[256][12];
    __shared__ float sDen[16];

    const int tid = threadIdx.x;
    if (tid < 16) sDen[tid] = 0.f;
    __syncthreads();

    float e[NCLS];
    #pragma unroll
    for (int c = 0; c < NCLS; ++c) {
        e[c] = __expf(Wout[(size_t)tid * NCLS + c]);
        sE[tid][c] = e[c];
    }
    #pragma unroll
    for (int c = 0; c < NCLS; ++c) {
        float v = e[c];
        for (int off = 32; off > 0; off >>= 1) v += __shfl_down(v, off);
        if ((tid & 63) == 0) atomicAdd(&sDen[c], v);
    }

    const int b0 = blockIdx.x * 16;
    #pragma unroll
    for (int v = 0; v < 4; ++v) {
        const int u = v * 256 + tid;
        const int row = u >> 6;
        const int c4 = (u & 63) * 4;
        const size_t base = (size_t)(b0 + row) * 512 + c4;
        const float4 p0 = *(const float4*)&R7[base];
        const float4 p1 = *(const float4*)&R7[base + 256];
        const float4 c0 = *(const float4*)&C7[c4];
        const float4 c1 = *(const float4*)&C7[256 + c4];
        sR[row][c4 + 0] = (p0.x * p1.x) / (c0.x * c1.x);
        sR[row][c4 + 1] = (p0.y * p1.y) / (c0.y * c1.y);
        sR[row][c4 + 2] = (p0.z * p1.z) / (c0.z * c1.z);
        sR[row][c4 + 3] = (p0.w * p1.w) / (c0.w * c1.w);
    }
    __syncthreads();

    const int ty = tid >> 4, tx = tid & 15;
    if (tx < NCLS) {
        float s = 0.f;
        for (int k = 0; k < Kk; ++k) s += sR[ty][k] * sE[k][tx];
        out[(size_t)(b0 + ty) * NCLS + tx] = s / sDen[tx];
    }
}

extern "C" void kernel_launch(void* const* d_in, const int* in_sizes, int n_in,
                              void* d_out, int out_size, void* d_ws, size_t ws_size,
                              hipStream_t stream)
{
    const float* x    = (const float*)d_in[0];
    const float* Win  = (const float*)d_in[1];
    const float* Wl[8];
    for (int lv = 0; lv < 8; ++lv) Wl[lv] = (const float*)d_in[2 + lv];
    const float* Wout = (const float*)d_in[10];
    float* out = (float*)d_out;

    char* wsb = (char*)d_ws;
    const size_t MB = 1024 * 1024;
    // bf16 proj buffers
    ushort* P0 = (ushort*)(wsb + 0);        // 32 MB  (L0 out, L1 in)
    ushort* P1 = (ushort*)(wsb + 32 * MB);  // 16 MB  (L1 out, L2 in)
    ushort* P2 = (ushort*)(wsb + 0);        //  8 MB  (L2 out, L3 in; reuses P0)
    ushort* P3 = (ushort*)(wsb + 8 * MB);   //  4 MB  (L3 out, L4 in)
    // fp32 raw accumulation buffers [12MB, 24MB) — zeroed below
    float* R4 = (float*)(wsb + 12 * MB);    // 4 MB
    float* C4 = (float*)(wsb + 16 * MB);    // 16 KB
    float* R5 = (float*)(wsb + 17 * MB);    // 2 MB
    float* C5 = (float*)(wsb + 19 * MB);    // 8 KB
    float* R6 = (float*)(wsb + 20 * MB);    // 1 MB
    float* C6 = (float*)(wsb + 21 * MB);    // 4 KB
    float* R7 = (float*)(wsb + 22 * MB);    // 0.5 MB
    float* C7 = (float*)(wsb + 23 * MB);    // 2 KB

    // zero the atomic region [12MB, 24MB)
    zero_kernel<<<1024, 256, 0, stream>>>((float4*)(wsb + 12 * MB),
                                          (int)(12 * MB / 16));

    // L0: FIRST -> NORM bf16
    level_kernel<0, false><<<dim3(8, 128, 1), 256, 0, stream>>>(
        x, Win, nullptr, nullptr, nullptr, Wl[0], P0, nullptr, nullptr, 128, 256);
    // L1-L3: NORM -> NORM bf16
    level_kernel<1, false><<<dim3(8, 64, 1), 256, 0, stream>>>(
        nullptr, nullptr, P0, nullptr, nullptr, Wl[1], P1, nullptr, nullptr, 64, 256);
    level_kernel<1, false><<<dim3(8, 32, 1), 256, 0, stream>>>(
        nullptr, nullptr, P1, nullptr, nullptr, Wl[2], P2, nullptr, nullptr, 32, 256);
    level_kernel<1, false><<<dim3(8, 16, 1), 256, 0, stream>>>(
        nullptr, nullptr, P2, nullptr, nullptr, Wl[3], P3, nullptr, nullptr, 16, 256);
    // L4: NORM in -> RAW out, K split 4
    level_kernel<1, true><<<dim3(8, 8, 4), 256, 0, stream>>>(
        nullptr, nullptr, P3, nullptr, nullptr, Wl[4], nullptr, R4, C4, 8, 64);
    // L5-L7: RAW in -> RAW out, K split 8
    level_kernel<2, true><<<dim3(8, 4, 8), 256, 0, stream>>>(
        nullptr, nullptr, nullptr, R4, C4, Wl[5], nullptr, R5, C5, 4, 32);
    level_kernel<2, true><<<dim3(8, 2, 8), 256, 0, stream>>>(
        nullptr, nullptr, nullptr, R5, C5, Wl[6], nullptr, R6, C6, 2, 32);
    level_kernel<2, true><<<dim3(8, 1, 8), 256, 0, stream>>>(
        nullptr, nullptr, nullptr, R6, C6, Wl[7], nullptr, R7, C7, 1, 32);

    // head
    out_kernel<<<dim3(16), 256, 0, stream>>>(R7, C7, Wout, out);
}

// Round 6
// 313.813 us; speedup vs baseline: 1.2704x; 1.2704x over previous
//
#include <hip/hip_runtime.h>
#include <stdint.h>

#define Kk 256
#define NCLS 10

typedef __attribute__((ext_vector_type(8))) short short8;
typedef __attribute__((ext_vector_type(4))) float f32x4;

__device__ __forceinline__ float bf2f(ushort u) {
    return __uint_as_float(((unsigned int)u) << 16);
}
__device__ __forceinline__ ushort f2bf(float f) {
    unsigned int u = __float_as_uint(f);
    u = (u + 0x7FFFu + ((u >> 16) & 1u)) >> 16;
    return (ushort)u;
}
__device__ __forceinline__ float tanh_fast(float v) {
    float t = __expf(2.f * v);
    return (t - 1.f) / (t + 1.f);
}
// async global->LDS, 16B per lane; LDS dest = wave-uniform base + lane*16
__device__ __forceinline__ void gll16(const void* g, void* s) {
    __builtin_amdgcn_global_load_lds(
        (const __attribute__((address_space(1))) void*)g,
        (__attribute__((address_space(3))) void*)s, 16, 0, 0);
}

// ---------------------------------------------------------------------------
// EXP pass: E[i,a,j,k] = bf16(exp(W[i,a,k,j])) (transposed), Rcp[i,a,j] =
// 1/sum_k exp. Block = (ia, 64-wide j tile), full K.
// ---------------------------------------------------------------------------
__device__ void exp_tile(const float* __restrict__ Wb, ushort* __restrict__ Eb,
                         float* __restrict__ rcp_row, const int j0)
{
    __shared__ float sT[64][68];
    __shared__ float sC[4][64];
    const int tid = threadIdx.x;
    const int lj = tid & 63;
    const int kq = tid >> 6;
    const int jj = (tid & 15) * 4;
    const int kk = tid >> 4;
    float csum = 0.f;

    for (int kb = 0; kb < 4; ++kb) {
        #pragma unroll
        for (int p = 0; p < 4; ++p) {
            const int k = kb * 64 + p * 16 + kk;
            *(float4*)&sT[p * 16 + kk][jj] = *(const float4*)&Wb[(size_t)k * 256 + j0 + jj];
        }
        __syncthreads();
        ushort pk[16];
        #pragma unroll
        for (int t = 0; t < 16; ++t) {
            const float e = __expf(sT[kq * 16 + t][lj]);
            csum += e;
            pk[t] = f2bf(e);
        }
        short8 v0, v1;
        #pragma unroll
        for (int e2 = 0; e2 < 8; ++e2) { v0[e2] = (short)pk[e2]; v1[e2] = (short)pk[8 + e2]; }
        ushort* dst = Eb + (size_t)(j0 + lj) * 256 + kb * 64 + kq * 16;
        *(short8*)dst = v0;
        *(short8*)(dst + 8) = v1;
        __syncthreads();
    }
    sC[kq][lj] = csum;
    __syncthreads();
    if (tid < 64)
        rcp_row[j0 + tid] = 1.f / (sC[0][tid] + sC[1][tid] + sC[2][tid] + sC[3][tid]);
}

__global__ __launch_bounds__(256)
void exp0_kernel(const float* __restrict__ W, ushort* __restrict__ E,
                 float* __restrict__ Rcp)
{
    const int ia = blockIdx.y;
    const int j0 = blockIdx.x * 64;
    exp_tile(W + (size_t)ia * 65536, E + ((size_t)ia << 16),
             Rcp + (size_t)ia * 256, j0);
}

__global__ __launch_bounds__(256)
void exp_rest_kernel(const float* __restrict__ W1, const float* __restrict__ W2,
                     const float* __restrict__ W3, const float* __restrict__ W4,
                     const float* __restrict__ W5, const float* __restrict__ W6,
                     const float* __restrict__ W7,
                     ushort* __restrict__ Ebase, float* __restrict__ RcpBase)
{
    int rem = blockIdx.x;
    int lvl = 1, n2 = 128;
    while (rem >= n2 * 4 && lvl < 7) { rem -= n2 * 4; n2 >>= 1; ++lvl; }
    const int jt = rem & 3;
    const int ia = rem >> 2;
    const float* W;
    switch (lvl) {
        case 1: W = W1; break; case 2: W = W2; break; case 3: W = W3; break;
        case 4: W = W4; break; case 5: W = W5; break; case 6: W = W6; break;
        default: W = W7; break;
    }
    size_t eoff = 0; int rrow = 256;
    for (int m = 1; m < lvl; ++m) { eoff += ((size_t)(256 >> m)) << 16; rrow += (256 >> m); }
    exp_tile(W + (size_t)ia * 65536,
             Ebase + eoff + ((size_t)ia << 16),
             RcpBase + (size_t)(rrow + ia) * 256, jt * 64);
}

// ---------------------------------------------------------------------------
// Level GEMM: H_out[b,i,j] = prod_a ( (sum_k A_a[b,k] * E[i,a,j,k]) * Rcp[i,a,j] )
// A_a = H[b, 2i+a, :] (bf16, materialized product) or tanh(x*Win) [TANH].
// BM=128(bh) x BN=64(jt), BK=32, both a in block, 4 waves (wm2 x wn2),
// wave tile 64b x 32j x 2a -> 16 mfma_16x16x32_bf16 per K-step per wave.
// LDS linear rows (64B) + XOR swizzle on 16B chunks: slot = c ^ ((row>>1)&3),
// applied on gll SOURCE and ds_read address (both-sides involution).
// ---------------------------------------------------------------------------
template<bool TANH>
__global__ __launch_bounds__(256, 3)
void level_kernel(const float* __restrict__ x,
                  const float* __restrict__ Win,
                  const ushort* __restrict__ H,
                  const ushort* __restrict__ E,
                  const float* __restrict__ Rcp,
                  ushort* __restrict__ Hout,
                  const int n)
{
    __shared__ __align__(16) char sA[2][2][128 * 64];  // [a][buf][row*64B]
    __shared__ __align__(16) char sE[2][2][64 * 64];   // [a][buf][jrow*64B]

    const int tid = threadIdx.x;
    const int bh  = blockIdx.x & 1;
    const int jt  = blockIdx.x >> 1;
    const int i   = blockIdx.y;
    const int b0  = bh * 128;
    const int j0  = jt * 64;
    const int np  = 2 * n;

    const int l   = tid & 63;
    const int l15 = l & 15;
    const int g   = l >> 4;
    const int w   = tid >> 6;
    const int wm  = w >> 1;
    const int wn  = w & 1;

    f32x4 acc[2][4][2];
    #pragma unroll
    for (int a2 = 0; a2 < 2; ++a2)
        #pragma unroll
        for (int mf = 0; mf < 4; ++mf)
            #pragma unroll
            for (int nf = 0; nf < 2; ++nf)
                acc[a2][mf][nf] = (f32x4){0.f, 0.f, 0.f, 0.f};

    float xv = 0.f;
    const int ta   = tid >> 7;
    const int trow = tid & 127;
    if (TANH) xv = x[(size_t)(b0 + trow) * 256 + (2 * i + ta)];

    auto stage = [&](int buf, int k0) {
        if (TANH) {
            const float* wrow = &Win[(size_t)(2 * i + ta) * 256 + k0];
            char* base = &sA[ta][buf][trow * 64];
            const int sr = (trow >> 1) & 3;
            #pragma unroll
            for (int c = 0; c < 4; ++c) {
                const float4 w0 = *(const float4*)&wrow[c * 8];
                const float4 w1 = *(const float4*)&wrow[c * 8 + 4];
                short8 v;
                v[0] = (short)f2bf(tanh_fast(xv * w0.x));
                v[1] = (short)f2bf(tanh_fast(xv * w0.y));
                v[2] = (short)f2bf(tanh_fast(xv * w0.z));
                v[3] = (short)f2bf(tanh_fast(xv * w0.w));
                v[4] = (short)f2bf(tanh_fast(xv * w1.x));
                v[5] = (short)f2bf(tanh_fast(xv * w1.y));
                v[6] = (short)f2bf(tanh_fast(xv * w1.z));
                v[7] = (short)f2bf(tanh_fast(xv * w1.w));
                *(short8*)(base + (((c ^ sr)) << 4)) = v;
            }
        } else {
            #pragma unroll
            for (int u0 = 0; u0 < 4; ++u0) {
                const int u   = w * 4 + u0;
                const int ua  = u >> 3;
                const int r16 = (u & 7) << 4;
                const int row = r16 + (l >> 2);
                const int c   = l & 3;
                const ushort* src = H
                    + ((size_t)(b0 + row) * np + (2 * i + ua)) * 256
                    + k0 + ((c ^ ((row >> 1) & 3)) << 3);
                gll16(src, &sA[ua][buf][r16 * 64]);
            }
        }
        #pragma unroll
        for (int v0 = 0; v0 < 2; ++v0) {
            const int v    = w * 2 + v0;
            const int ea   = v >> 2;
            const int jr16 = (v & 3) << 4;
            const int jr   = jr16 + (l >> 2);
            const int c    = l & 3;
            const ushort* src = E + ((size_t)(2 * i + ea) << 16)
                + (size_t)(j0 + jr) * 256
                + k0 + ((c ^ ((jr >> 1) & 3)) << 3);
            gll16(src, &sE[ea][buf][jr16 * 64]);
        }
    };

    stage(0, 0);
    __syncthreads();

    for (int t = 0; t < 8; ++t) {
        const int buf = t & 1;
        if (t < 7) stage(buf ^ 1, (t + 1) * 32);

        short8 afr[2][4];
        short8 bfr[2][2];
        #pragma unroll
        for (int a2 = 0; a2 < 2; ++a2) {
            #pragma unroll
            for (int nf = 0; nf < 2; ++nf) {
                const int jr = wn * 32 + nf * 16 + l15;
                bfr[a2][nf] = *(const short8*)&sE[a2][buf][jr * 64 + ((g ^ ((jr >> 1) & 3)) << 4)];
            }
            #pragma unroll
            for (int mf = 0; mf < 4; ++mf) {
                const int row = wm * 64 + mf * 16 + l15;
                afr[a2][mf] = *(const short8*)&sA[a2][buf][row * 64 + ((g ^ ((row >> 1) & 3)) << 4)];
            }
        }
        #pragma unroll
        for (int a2 = 0; a2 < 2; ++a2)
            #pragma unroll
            for (int mf = 0; mf < 4; ++mf)
                #pragma unroll
                for (int nf = 0; nf < 2; ++nf)
                    acc[a2][mf][nf] = __builtin_amdgcn_mfma_f32_16x16x32_bf16(
                        afr[a2][mf], bfr[a2][nf], acc[a2][mf][nf], 0, 0, 0);
        __syncthreads();
    }

    // epilogue: normalize both sides, pair-product, write H_out bf16
    float rc[2][2];
    #pragma unroll
    for (int a2 = 0; a2 < 2; ++a2)
        #pragma unroll
        for (int nf = 0; nf < 2; ++nf)
            rc[a2][nf] = Rcp[(size_t)(2 * i + a2) * 256 + j0 + wn * 32 + nf * 16 + l15];

    #pragma unroll
    for (int mf = 0; mf < 4; ++mf)
        #pragma unroll
        for (int nf = 0; nf < 2; ++nf) {
            const int j = j0 + wn * 32 + nf * 16 + l15;
            #pragma unroll
            for (int r = 0; r < 4; ++r) {
                const int b = b0 + wm * 64 + mf * 16 + g * 4 + r;
                const float v0 = acc[0][mf][nf][r] * rc[0][nf];
                const float v1 = acc[1][mf][nf][r] * rc[1][nf];
                Hout[((size_t)b * n + i) * 256 + j] = f2bf(v0 * v1);
            }
        }
}

// ---------------------------------------------------------------------------
// Head: out[b,c] = sum_k root[b,k]*exp(Wout[k,c]) / colsum_c  (root bf16)
// ---------------------------------------------------------------------------
__global__ __launch_bounds__(256)
void out_kernel(const ushort* __restrict__ root, const float* __restrict__ Wout,
                float* __restrict__ out)
{
    __shared__ float sR[16][260];
    __shared__ float sE2[256][12];
    __shared__ float sDen[16];
    const int tid = threadIdx.x;
    if (tid < 16) sDen[tid] = 0.f;
    __syncthreads();
    float e[NCLS];
    #pragma unroll
    for (int c = 0; c < NCLS; ++c) {
        e[c] = __expf(Wout[(size_t)tid * NCLS + c]);
        sE2[tid][c] = e[c];
    }
    #pragma unroll
    for (int c = 0; c < NCLS; ++c) {
        float v = e[c];
        for (int off = 32; off > 0; off >>= 1) v += __shfl_down(v, off);
        if ((tid & 63) == 0) atomicAdd(&sDen[c], v);
    }
    const int b0 = blockIdx.x * 16;
    #pragma unroll
    for (int v = 0; v < 4; ++v) {
        const int u = v * 256 + tid;
        const int row = u >> 6;
        const int c4 = (u & 63) * 4;
        const ushort4 p = *(const ushort4*)&root[(size_t)(b0 + row) * 256 + c4];
        sR[row][c4 + 0] = bf2f(p.x);
        sR[row][c4 + 1] = bf2f(p.y);
        sR[row][c4 + 2] = bf2f(p.z);
        sR[row][c4 + 3] = bf2f(p.w);
    }
    __syncthreads();
    const int ty = tid >> 4, tx = tid & 15;
    if (tx < NCLS) {
        float s = 0.f;
        for (int k = 0; k < Kk; ++k) s += sR[ty][k] * sE2[k][tx];
        out[(size_t)(b0 + ty) * NCLS + tx] = s / sDen[tx];
    }
}

extern "C" void kernel_launch(void* const* d_in, const int* in_sizes, int n_in,
                              void* d_out, int out_size, void* d_ws, size_t ws_size,
                              hipStream_t stream)
{
    const float* x    = (const float*)d_in[0];
    const float* Win  = (const float*)d_in[1];
    const float* Wl[8];
    for (int lv = 0; lv < 8; ++lv) Wl[lv] = (const float*)d_in[2 + lv];
    const float* Wout = (const float*)d_in[10];
    float* out = (float*)d_out;

    // Workspace (59.2 MB):
    //  R1 [0, 32MiB):      E0 (256x65536 u) during L0; then E1..E7 (254x65536 u)
    //  R2 [32MiB, 48MiB):  H1, H3, H5, H7
    //  R3 [48MiB, 56MiB):  H2, H4, H6, root
    //  RC [56MiB, +522KB): Rcp rows: level0 at 0, level l at 256+sum(2n)
    char* wsb = (char*)d_ws;
    ushort* R1 = (ushort*)wsb;
    ushort* R2 = (ushort*)(wsb + 33554432);
    ushort* R3 = (ushort*)(wsb + 50331648);
    float*  RC = (float*)(wsb + 58720256);

    // E0 + Rcp0
    exp0_kernel<<<dim3(4, 256), 256, 0, stream>>>(Wl[0], R1, RC);
    // L0: tanh rank-1 A, writes H1 -> R2
    level_kernel<true><<<dim3(8, 128), 256, 0, stream>>>(x, Win, nullptr, R1, RC, R2, 128);
    // E1..E7 into R1 (E0 dead), Rcp rows 256..
    exp_rest_kernel<<<dim3(1016), 256, 0, stream>>>(Wl[1], Wl[2], Wl[3], Wl[4],
                                                    Wl[5], Wl[6], Wl[7], R1, RC);
    // L1..L7
    size_t eoff = 0;
    size_t rrow = 256;
    const ushort* hin = R2;
    ushort* hout = nullptr;
    for (int lv = 1; lv < 8; ++lv) {
        const int n = 128 >> lv;
        hout = (lv & 1) ? R3 : R2;
        level_kernel<false><<<dim3(8, n), 256, 0, stream>>>(
            nullptr, nullptr, hin, R1 + eoff, RC + rrow * 256, hout, n);
        hin = hout;
        eoff += ((size_t)(2 * n)) << 16;
        rrow += 2 * n;
    }
    // head: root in R3
    out_kernel<<<dim3(16), 256, 0, stream>>>(hin, Wout, out);
}

// Round 7
// 307.279 us; speedup vs baseline: 1.2974x; 1.0213x over previous
//
#include <hip/hip_runtime.h>

#define NCLS 10

typedef __attribute__((ext_vector_type(8))) short short8;
typedef __attribute__((ext_vector_type(4))) float f32x4;

__device__ __forceinline__ float bf2f(ushort u) {
    return __uint_as_float(((unsigned int)u) << 16);
}
__device__ __forceinline__ ushort f2bf(float f) {
    unsigned int u = __float_as_uint(f);
    u = (u + 0x7FFFu + ((u >> 16) & 1u)) >> 16;
    return (ushort)u;
}
__device__ __forceinline__ float tanh_fast(float v) {
    float t = __expf(2.f * v);
    return (t - 1.f) / (t + 1.f);
}
__device__ __forceinline__ void gll16(const void* g, void* s) {
    __builtin_amdgcn_global_load_lds(
        (const __attribute__((address_space(1))) void*)g,
        (__attribute__((address_space(3))) void*)s, 16, 0, 0);
}

// ---------------------------------------------------------------------------
// exp tile: E[j][k] = bf16(exp(W[k][j])) for a 64-wide j stripe, full K=256;
// rcp_row[j] = 1/colsum.
// ---------------------------------------------------------------------------
__device__ void exp_tile(const float* __restrict__ Wb, ushort* __restrict__ Eb,
                         float* __restrict__ rcp_row, const int j0)
{
    __shared__ float sT[64][68];
    __shared__ float sC[4][64];
    const int tid = threadIdx.x;
    const int lj = tid & 63;
    const int kq = tid >> 6;
    const int jj = (tid & 15) * 4;
    const int kk = tid >> 4;
    float csum = 0.f;

    for (int kb = 0; kb < 4; ++kb) {
        #pragma unroll
        for (int p = 0; p < 4; ++p) {
            const int k = kb * 64 + p * 16 + kk;
            *(float4*)&sT[p * 16 + kk][jj] = *(const float4*)&Wb[(size_t)k * 256 + j0 + jj];
        }
        __syncthreads();
        ushort pk[16];
        #pragma unroll
        for (int t = 0; t < 16; ++t) {
            const float e = __expf(sT[kq * 16 + t][lj]);
            csum += e;
            pk[t] = f2bf(e);
        }
        short8 v0, v1;
        #pragma unroll
        for (int e2 = 0; e2 < 8; ++e2) { v0[e2] = (short)pk[e2]; v1[e2] = (short)pk[8 + e2]; }
        ushort* dst = Eb + (size_t)(j0 + lj) * 256 + kb * 64 + kq * 16;
        *(short8*)dst = v0;
        *(short8*)(dst + 8) = v1;
        __syncthreads();
    }
    sC[kq][lj] = csum;
    __syncthreads();
    if (tid < 64)
        rcp_row[j0 + tid] = 1.f / (sC[0][tid] + sC[1][tid] + sC[2][tid] + sC[3][tid]);
}

// prep1: blocks [0,1024) = E0 + Rcp0; blocks [1024,1280) = H0 = tanh(x*Win)
__global__ __launch_bounds__(256)
void prep1_kernel(const float* __restrict__ W0, const float* __restrict__ x,
                  const float* __restrict__ Win, ushort* __restrict__ E0,
                  float* __restrict__ Rcp0, ushort* __restrict__ H0)
{
    const int bid = blockIdx.x;
    if (bid < 1024) {
        const int ia = bid >> 2, jt = bid & 3;
        exp_tile(W0 + (size_t)ia * 65536, E0 + ((size_t)ia << 16),
                 Rcp0 + (size_t)ia * 256, jt * 64);
    } else {
        __shared__ float sX[256];
        const int d = bid - 1024;
        const int tid = threadIdx.x;
        sX[tid] = x[(size_t)tid * 256 + d];
        __syncthreads();
        const int k2 = (tid & 127) * 2;
        const int boff = tid >> 7;
        const float2 wv = *(const float2*)&Win[(size_t)d * 256 + k2];
        for (int b2 = 0; b2 < 256; b2 += 2) {
            const int b = b2 + boff;
            const float xb = sX[b];
            const unsigned int u0 = f2bf(tanh_fast(xb * wv.x));
            const unsigned int u1 = f2bf(tanh_fast(xb * wv.y));
            *(unsigned int*)&H0[((size_t)b * 256 + d) * 256 + k2] = u0 | (u1 << 16);
        }
    }
}

// fallback E0-only pass
__global__ __launch_bounds__(256)
void exp0_kernel(const float* __restrict__ W, ushort* __restrict__ E,
                 float* __restrict__ Rcp)
{
    const int ia = blockIdx.y;
    const int j0 = blockIdx.x * 64;
    exp_tile(W + (size_t)ia * 65536, E + ((size_t)ia << 16),
             Rcp + (size_t)ia * 256, j0);
}

// prep2: E1..E7 (+Rcp rows 256..) — 1016 blocks
__global__ __launch_bounds__(256)
void prep2_kernel(const float* __restrict__ W1, const float* __restrict__ W2,
                  const float* __restrict__ W3, const float* __restrict__ W4,
                  const float* __restrict__ W5, const float* __restrict__ W6,
                  const float* __restrict__ W7,
                  ushort* __restrict__ Ebase, float* __restrict__ RcpBase)
{
    int rem = blockIdx.x;
    int lvl = 1, n2 = 128;
    while (rem >= n2 * 4 && lvl < 7) { rem -= n2 * 4; n2 >>= 1; ++lvl; }
    const int jt = rem & 3;
    const int ia = rem >> 2;
    const float* W;
    switch (lvl) {
        case 1: W = W1; break; case 2: W = W2; break; case 3: W = W3; break;
        case 4: W = W4; break; case 5: W = W5; break; case 6: W = W6; break;
        default: W = W7; break;
    }
    size_t eoff = 0; int rrow = 256;
    for (int m = 1; m < lvl; ++m) { eoff += ((size_t)(256 >> m)) << 16; rrow += (256 >> m); }
    exp_tile(W + (size_t)ia * 65536,
             Ebase + eoff + ((size_t)ia << 16),
             RcpBase + (size_t)(rrow + ia) * 256, jt * 64);
}

// ---------------------------------------------------------------------------
// Level GEMM, tile BM x 64, BK=32, both a in block; 4 waves = WR x WC.
// H_out[b,i,j] = prod_a ( (sum_k A_a[b,k]*E[i,a,j,k]) * Rcp[i,a,j] )
// A from H (gll16) or tanh(x*Win) in-staging (TANH, BM=128 fallback only).
// ---------------------------------------------------------------------------
template<int BM, int WR, int WC, int LB, bool TANH>
__global__ __launch_bounds__(256, LB)
void level_kernel(const float* __restrict__ x, const float* __restrict__ Win,
                  const ushort* __restrict__ H, const ushort* __restrict__ E,
                  const float* __restrict__ Rcp, ushort* __restrict__ Hout,
                  const int n)
{
    constexpr int MF = BM / (16 * WR);
    constexpr int NF = 64 / (16 * WC);
    constexpr int NBH = 256 / BM;
    constexpr int AUNITS = 2 * BM / 16;
    constexpr int UITER = (AUNITS + 3) / 4;

    __shared__ __align__(16) char sA[2][2][BM * 64];
    __shared__ __align__(16) char sB[2][2][64 * 64];

    const int tid = threadIdx.x;
    const int bh  = blockIdx.x % NBH;
    const int jt  = blockIdx.x / NBH;
    const int i   = blockIdx.y;
    const int b0  = bh * BM;
    const int j0  = jt * 64;
    const int np  = 2 * n;

    const int l   = tid & 63;
    const int l15 = l & 15;
    const int g   = l >> 4;
    const int w   = tid >> 6;
    const int wm  = w / WC;
    const int wn  = w % WC;

    f32x4 acc[2][MF][NF];
    #pragma unroll
    for (int a2 = 0; a2 < 2; ++a2)
        #pragma unroll
        for (int mf = 0; mf < MF; ++mf)
            #pragma unroll
            for (int nf = 0; nf < NF; ++nf)
                acc[a2][mf][nf] = (f32x4){0.f, 0.f, 0.f, 0.f};

    float xv = 0.f;
    int ta = 0, trow = 0;
    if (TANH) {
        ta = tid >> 7; trow = tid & 127;
        xv = x[(size_t)(b0 + trow) * 256 + 2 * i + ta];
    }

    auto stage = [&](int buf, int k0) {
        if constexpr (TANH) {
            const float* wrow = &Win[(size_t)(2 * i + ta) * 256 + k0];
            char* base = &sA[ta][buf][trow * 64];
            const int sr = (trow >> 1) & 3;
            #pragma unroll
            for (int c = 0; c < 4; ++c) {
                const float4 w0 = *(const float4*)&wrow[c * 8];
                const float4 w1 = *(const float4*)&wrow[c * 8 + 4];
                short8 v;
                v[0] = (short)f2bf(tanh_fast(xv * w0.x));
                v[1] = (short)f2bf(tanh_fast(xv * w0.y));
                v[2] = (short)f2bf(tanh_fast(xv * w0.z));
                v[3] = (short)f2bf(tanh_fast(xv * w0.w));
                v[4] = (short)f2bf(tanh_fast(xv * w1.x));
                v[5] = (short)f2bf(tanh_fast(xv * w1.y));
                v[6] = (short)f2bf(tanh_fast(xv * w1.z));
                v[7] = (short)f2bf(tanh_fast(xv * w1.w));
                *(short8*)(base + ((c ^ sr) << 4)) = v;
            }
        } else {
            #pragma unroll
            for (int uu = 0; uu < UITER; ++uu) {
                const int u = w + uu * 4;
                if (u < AUNITS) {
                    const int ua  = u / (BM / 16);
                    const int r16 = (u % (BM / 16)) * 16;
                    const int row = r16 + (l >> 2);
                    const int c   = l & 3;
                    const ushort* src = H
                        + ((size_t)(b0 + row) * np + (2 * i + ua)) * 256
                        + k0 + ((c ^ ((row >> 1) & 3)) << 3);
                    gll16(src, &sA[ua][buf][r16 * 64]);
                }
            }
        }
        #pragma unroll
        for (int vv = 0; vv < 2; ++vv) {
            const int v    = w + vv * 4;
            const int ea   = v >> 2;
            const int jr16 = (v & 3) * 16;
            const int jr   = jr16 + (l >> 2);
            const int c    = l & 3;
            const ushort* src = E + ((size_t)(2 * i + ea) << 16)
                + (size_t)(j0 + jr) * 256
                + k0 + ((c ^ ((jr >> 1) & 3)) << 3);
            gll16(src, &sB[ea][buf][jr16 * 64]);
        }
    };

    stage(0, 0);
    __syncthreads();

    for (int t = 0; t < 8; ++t) {
        const int buf = t & 1;
        if (t < 7) stage(buf ^ 1, (t + 1) * 32);

        short8 afr[2][MF];
        short8 bfr[2][NF];
        #pragma unroll
        for (int a2 = 0; a2 < 2; ++a2) {
            #pragma unroll
            for (int nf = 0; nf < NF; ++nf) {
                const int jr = wn * (NF * 16) + nf * 16 + l15;
                bfr[a2][nf] = *(const short8*)&sB[a2][buf][jr * 64 + ((g ^ ((jr >> 1) & 3)) << 4)];
            }
            #pragma unroll
            for (int mf = 0; mf < MF; ++mf) {
                const int row = wm * (MF * 16) + mf * 16 + l15;
                afr[a2][mf] = *(const short8*)&sA[a2][buf][row * 64 + ((g ^ ((row >> 1) & 3)) << 4)];
            }
        }
        #pragma unroll
        for (int a2 = 0; a2 < 2; ++a2)
            #pragma unroll
            for (int mf = 0; mf < MF; ++mf)
                #pragma unroll
                for (int nf = 0; nf < NF; ++nf)
                    acc[a2][mf][nf] = __builtin_amdgcn_mfma_f32_16x16x32_bf16(
                        afr[a2][mf], bfr[a2][nf], acc[a2][mf][nf], 0, 0, 0);
        __syncthreads();
    }

    float rc[2][NF];
    #pragma unroll
    for (int a2 = 0; a2 < 2; ++a2)
        #pragma unroll
        for (int nf = 0; nf < NF; ++nf)
            rc[a2][nf] = Rcp[(size_t)(2 * i + a2) * 256 + j0 + wn * (NF * 16) + nf * 16 + l15];

    #pragma unroll
    for (int mf = 0; mf < MF; ++mf)
        #pragma unroll
        for (int nf = 0; nf < NF; ++nf) {
            const int j = j0 + wn * (NF * 16) + nf * 16 + l15;
            #pragma unroll
            for (int r = 0; r < 4; ++r) {
                const int b = b0 + wm * (MF * 16) + mf * 16 + g * 4 + r;
                const float v0 = acc[0][mf][nf][r] * rc[0][nf];
                const float v1 = acc[1][mf][nf][r] * rc[1][nf];
                Hout[((size_t)b * n + i) * 256 + j] = f2bf(v0 * v1);
            }
        }
}

// ---------------------------------------------------------------------------
// Head
// ---------------------------------------------------------------------------
__global__ __launch_bounds__(256)
void out_kernel(const ushort* __restrict__ root, const float* __restrict__ Wout,
                float* __restrict__ out)
{
    __shared__ float sR[16][260];
    __shared__ float sE2[256][12];
    __shared__ float sDen[16];
    const int tid = threadIdx.x;
    if (tid < 16) sDen[tid] = 0.f;
    __syncthreads();
    float e[NCLS];
    #pragma unroll
    for (int c = 0; c < NCLS; ++c) {
        e[c] = __expf(Wout[(size_t)tid * NCLS + c]);
        sE2[tid][c] = e[c];
    }
    #pragma unroll
    for (int c = 0; c < NCLS; ++c) {
        float v = e[c];
        for (int off = 32; off > 0; off >>= 1) v += __shfl_down(v, off);
        if ((tid & 63) == 0) atomicAdd(&sDen[c], v);
    }
    const int b0 = blockIdx.x * 16;
    #pragma unroll
    for (int v = 0; v < 4; ++v) {
        const int u = v * 256 + tid;
        const int row = u >> 6;
        const int c4 = (u & 63) * 4;
        const ushort4 p = *(const ushort4*)&root[(size_t)(b0 + row) * 256 + c4];
        sR[row][c4 + 0] = bf2f(p.x);
        sR[row][c4 + 1] = bf2f(p.y);
        sR[row][c4 + 2] = bf2f(p.z);
        sR[row][c4 + 3] = bf2f(p.w);
    }
    __syncthreads();
    const int ty = tid >> 4, tx = tid & 15;
    if (tx < NCLS) {
        float s = 0.f;
        for (int k = 0; k < 256; ++k) s += sR[ty][k] * sE2[k][tx];
        out[(size_t)(b0 + ty) * NCLS + tx] = s / sDen[tx];
    }
}

extern "C" void kernel_launch(void* const* d_in, const int* in_sizes, int n_in,
                              void* d_out, int out_size, void* d_ws, size_t ws_size,
                              hipStream_t stream)
{
    const float* x    = (const float*)d_in[0];
    const float* Win  = (const float*)d_in[1];
    const float* Wl[8];
    for (int lv = 0; lv < 8; ++lv) Wl[lv] = (const float*)d_in[2 + lv];
    const float* Wout = (const float*)d_in[10];
    float* out = (float*)d_out;

    char* wsb = (char*)d_ws;
    // E offsets (in 64Ki-ushort matrices) for levels 1..7 within the E region
    static const size_t ecum[8] = {0, 0, 128, 192, 224, 240, 248, 252};

    if (ws_size >= 84408320ull) {
        // Main layout: A [0,32Mi): E0 then H2/H4/H6/root (A1 = +16Mi: H3/H5/H7)
        //              C [32Mi,48Mi): H1
        //              B [48Mi,80Mi): H0 then E1..E7
        //              RC [80Mi, +522240)
        ushort* A0 = (ushort*)wsb;
        ushort* A1 = (ushort*)(wsb + 16777216);
        ushort* C  = (ushort*)(wsb + 33554432);
        ushort* B  = (ushort*)(wsb + 50331648);
        float*  RC = (float*)(wsb + 83886080);

        prep1_kernel<<<dim3(1280), 256, 0, stream>>>(Wl[0], x, Win, A0, RC, B);
        level_kernel<128, 2, 2, 3, false><<<dim3(8, 128), 256, 0, stream>>>(
            nullptr, nullptr, B, A0, RC, C, 128);
        prep2_kernel<<<dim3(1016), 256, 0, stream>>>(
            Wl[1], Wl[2], Wl[3], Wl[4], Wl[5], Wl[6], Wl[7], B, RC);

        level_kernel<64, 2, 2, 4, false><<<dim3(16, 64), 256, 0, stream>>>(
            nullptr, nullptr, C, B + (ecum[1] << 16), RC + (256 + ecum[1]) * 256, A0, 64);
        level_kernel<64, 2, 2, 4, false><<<dim3(16, 32), 256, 0, stream>>>(
            nullptr, nullptr, A0, B + (ecum[2] << 16), RC + (256 + ecum[2]) * 256, A1, 32);
        level_kernel<32, 2, 2, 4, false><<<dim3(32, 16), 256, 0, stream>>>(
            nullptr, nullptr, A1, B + (ecum[3] << 16), RC + (256 + ecum[3]) * 256, A0, 16);
        level_kernel<32, 2, 2, 4, false><<<dim3(32, 8), 256, 0, stream>>>(
            nullptr, nullptr, A0, B + (ecum[4] << 16), RC + (256 + ecum[4]) * 256, A1, 8);
        level_kernel<16, 1, 4, 4, false><<<dim3(64, 4), 256, 0, stream>>>(
            nullptr, nullptr, A1, B + (ecum[5] << 16), RC + (256 + ecum[5]) * 256, A0, 4);
        level_kernel<16, 1, 4, 4, false><<<dim3(64, 2), 256, 0, stream>>>(
            nullptr, nullptr, A0, B + (ecum[6] << 16), RC + (256 + ecum[6]) * 256, A1, 2);
        level_kernel<16, 1, 4, 4, false><<<dim3(64, 1), 256, 0, stream>>>(
            nullptr, nullptr, A1, B + (ecum[7] << 16), RC + (256 + ecum[7]) * 256, A0, 1);
        out_kernel<<<dim3(16), 256, 0, stream>>>(A0, Wout, out);
    } else {
        // Fallback (proven 56.5Mi layout): tanh stays inside L0
        ushort* R1 = (ushort*)wsb;                    // E0 then E1..E7
        ushort* R2 = (ushort*)(wsb + 33554432);       // H1/H3/H5/H7
        ushort* R3 = (ushort*)(wsb + 50331648);       // H2/H4/H6/root
        float*  RC = (float*)(wsb + 58720256);

        exp0_kernel<<<dim3(4, 256), 256, 0, stream>>>(Wl[0], R1, RC);
        level_kernel<128, 2, 2, 3, true><<<dim3(8, 128), 256, 0, stream>>>(
            x, Win, nullptr, R1, RC, R2, 128);
        prep2_kernel<<<dim3(1016), 256, 0, stream>>>(
            Wl[1], Wl[2], Wl[3], Wl[4], Wl[5], Wl[6], Wl[7], R1, RC);

        level_kernel<64, 2, 2, 4, false><<<dim3(16, 64), 256, 0, stream>>>(
            nullptr, nullptr, R2, R1 + (ecum[1] << 16), RC + (256 + ecum[1]) * 256, R3, 64);
        level_kernel<64, 2, 2, 4, false><<<dim3(16, 32), 256, 0, stream>>>(
            nullptr, nullptr, R3, R1 + (ecum[2] << 16), RC + (256 + ecum[2]) * 256, R2, 32);
        level_kernel<32, 2, 2, 4, false><<<dim3(32, 16), 256, 0, stream>>>(
            nullptr, nullptr, R2, R1 + (ecum[3] << 16), RC + (256 + ecum[3]) * 256, R3, 16);
        level_kernel<32, 2, 2, 4, false><<<dim3(32, 8), 256, 0, stream>>>(
            nullptr, nullptr, R3, R1 + (ecum[4] << 16), RC + (256 + ecum[4]) * 256, R2, 8);
        level_kernel<16, 1, 4, 4, false><<<dim3(64, 4), 256, 0, stream>>>(
            nullptr, nullptr, R2, R1 + (ecum[5] << 16), RC + (256 + ecum[5]) * 256, R3, 4);
        level_kernel<16, 1, 4, 4, false><<<dim3(64, 2), 256, 0, stream>>>(
            nullptr, nullptr, R3, R1 + (ecum[6] << 16), RC + (256 + ecum[6]) * 256, R2, 2);
        level_kernel<16, 1, 4, 4, false><<<dim3(64, 1), 256, 0, stream>>>(
            nullptr, nullptr, R2, R1 + (ecum[7] << 16), RC + (256 + ecum[7]) * 256, R3, 1);
        out_kernel<<<dim3(16), 256, 0, stream>>>(R3, Wout, out);
    }
}

// Round 8
// 272.934 us; speedup vs baseline: 1.4606x; 1.1258x over previous
//
#include <hip/hip_runtime.h>

#define NCLS 10

typedef __attribute__((ext_vector_type(8))) short short8;
typedef __attribute__((ext_vector_type(4))) float f32x4;

__device__ __forceinline__ float bf2f(ushort u) {
    return __uint_as_float(((unsigned int)u) << 16);
}
__device__ __forceinline__ ushort f2bf(float f) {
    unsigned int u = __float_as_uint(f);
    u = (u + 0x7FFFu + ((u >> 16) & 1u)) >> 16;
    return (ushort)u;
}
__device__ __forceinline__ float tanh_fast(float v) {
    float t = __expf(2.f * v);
    return (t - 1.f) / (t + 1.f);
}
__device__ __forceinline__ void gll16(const void* g, void* s) {
    __builtin_amdgcn_global_load_lds(
        (const __attribute__((address_space(1))) void*)g,
        (__attribute__((address_space(3))) void*)s, 16, 0, 0);
}

// ---------------------------------------------------------------------------
// exp tile: E[j][k] = bf16(exp(W[k][j])) for a 64-wide j stripe, full K=256;
// rcp_row[j] = 1/colsum.
// ---------------------------------------------------------------------------
__device__ void exp_tile(const float* __restrict__ Wb, ushort* __restrict__ Eb,
                         float* __restrict__ rcp_row, const int j0)
{
    __shared__ float sT[64][68];
    __shared__ float sC[4][64];
    const int tid = threadIdx.x;
    const int lj = tid & 63;
    const int kq = tid >> 6;
    const int jj = (tid & 15) * 4;
    const int kk = tid >> 4;
    float csum = 0.f;

    for (int kb = 0; kb < 4; ++kb) {
        #pragma unroll
        for (int p = 0; p < 4; ++p) {
            const int k = kb * 64 + p * 16 + kk;
            *(float4*)&sT[p * 16 + kk][jj] = *(const float4*)&Wb[(size_t)k * 256 + j0 + jj];
        }
        __syncthreads();
        ushort pk[16];
        #pragma unroll
        for (int t = 0; t < 16; ++t) {
            const float e = __expf(sT[kq * 16 + t][lj]);
            csum += e;
            pk[t] = f2bf(e);
        }
        short8 v0, v1;
        #pragma unroll
        for (int e2 = 0; e2 < 8; ++e2) { v0[e2] = (short)pk[e2]; v1[e2] = (short)pk[8 + e2]; }
        ushort* dst = Eb + (size_t)(j0 + lj) * 256 + kb * 64 + kq * 16;
        *(short8*)dst = v0;
        *(short8*)(dst + 8) = v1;
        __syncthreads();
    }
    sC[kq][lj] = csum;
    __syncthreads();
    if (tid < 64)
        rcp_row[j0 + tid] = 1.f / (sC[0][tid] + sC[1][tid] + sC[2][tid] + sC[3][tid]);
}

// prep1: blocks [0,1024) = E0 + Rcp0; blocks [1024,1280) = H0 = tanh(x*Win)
__global__ __launch_bounds__(256)
void prep1_kernel(const float* __restrict__ W0, const float* __restrict__ x,
                  const float* __restrict__ Win, ushort* __restrict__ E0,
                  float* __restrict__ Rcp0, ushort* __restrict__ H0)
{
    const int bid = blockIdx.x;
    if (bid < 1024) {
        const int ia = bid >> 2, jt = bid & 3;
        exp_tile(W0 + (size_t)ia * 65536, E0 + ((size_t)ia << 16),
                 Rcp0 + (size_t)ia * 256, jt * 64);
    } else {
        __shared__ float sX[256];
        const int d = bid - 1024;
        const int tid = threadIdx.x;
        sX[tid] = x[(size_t)tid * 256 + d];
        __syncthreads();
        const int k2 = (tid & 127) * 2;
        const int boff = tid >> 7;
        const float2 wv = *(const float2*)&Win[(size_t)d * 256 + k2];
        for (int b2 = 0; b2 < 256; b2 += 2) {
            const int b = b2 + boff;
            const float xb = sX[b];
            const unsigned int u0 = f2bf(tanh_fast(xb * wv.x));
            const unsigned int u1 = f2bf(tanh_fast(xb * wv.y));
            *(unsigned int*)&H0[((size_t)b * 256 + d) * 256 + k2] = u0 | (u1 << 16);
        }
    }
}

// fallback E0-only pass
__global__ __launch_bounds__(256)
void exp0_kernel(const float* __restrict__ W, ushort* __restrict__ E,
                 float* __restrict__ Rcp)
{
    const int ia = blockIdx.y;
    const int j0 = blockIdx.x * 64;
    exp_tile(W + (size_t)ia * 65536, E + ((size_t)ia << 16),
             Rcp + (size_t)ia * 256, j0);
}

// prep2: E1..E7 (+Rcp rows 256..) — 1016 blocks
__global__ __launch_bounds__(256)
void prep2_kernel(const float* __restrict__ W1, const float* __restrict__ W2,
                  const float* __restrict__ W3, const float* __restrict__ W4,
                  const float* __restrict__ W5, const float* __restrict__ W6,
                  const float* __restrict__ W7,
                  ushort* __restrict__ Ebase, float* __restrict__ RcpBase)
{
    int rem = blockIdx.x;
    int lvl = 1, n2 = 128;
    while (rem >= n2 * 4 && lvl < 7) { rem -= n2 * 4; n2 >>= 1; ++lvl; }
    const int jt = rem & 3;
    const int ia = rem >> 2;
    const float* W;
    switch (lvl) {
        case 1: W = W1; break; case 2: W = W2; break; case 3: W = W3; break;
        case 4: W = W4; break; case 5: W = W5; break; case 6: W = W6; break;
        default: W = W7; break;
    }
    size_t eoff = 0; int rrow = 256;
    for (int m = 1; m < lvl; ++m) { eoff += ((size_t)(256 >> m)) << 16; rrow += (256 >> m); }
    exp_tile(W + (size_t)ia * 65536,
             Ebase + eoff + ((size_t)ia << 16),
             RcpBase + (size_t)(rrow + ia) * 256, jt * 64);
}

// ---------------------------------------------------------------------------
// Level GEMM, tile BM x 64, BK=32, both a in block; 4 waves = WR x WC.
// H_out[b,i,j] = prod_a ( (sum_k A_a[b,k]*E[i,a,j,k]) * Rcp[i,a,j] )
// Grid is 1-D, bid = s*n + i  (s = slice = bh + jt*NBH, i = pair index).
// Since consecutive linear ids round-robin across the 8 XCDs and n % 8 == 0
// for the big levels, all blocks of pair i land on the SAME XCD -> its L2
// serves the shared A-panels / E-stripes instead of redundant HBM fetches.
// ---------------------------------------------------------------------------
template<int BM, int WR, int WC, int LB, bool TANH>
__global__ __launch_bounds__(256, LB)
void level_kernel(const float* __restrict__ x, const float* __restrict__ Win,
                  const ushort* __restrict__ H, const ushort* __restrict__ E,
                  const float* __restrict__ Rcp, ushort* __restrict__ Hout,
                  const int n, const int lg)
{
    constexpr int MF = BM / (16 * WR);
    constexpr int NF = 64 / (16 * WC);
    constexpr int NBH = 256 / BM;
    constexpr int AUNITS = 2 * BM / 16;
    constexpr int UITER = (AUNITS + 3) / 4;

    __shared__ __align__(16) char sA[2][2][BM * 64];
    __shared__ __align__(16) char sB[2][2][64 * 64];

    const int tid = threadIdx.x;
    const int bid = blockIdx.x;
    const int i   = bid & (n - 1);          // pair index (n is a power of 2)
    const int s   = bid >> lg;              // slice = bh + jt*NBH
    const int bh  = s % NBH;
    const int jt  = s / NBH;
    const int b0  = bh * BM;
    const int j0  = jt * 64;
    const int np  = 2 * n;

    const int l   = tid & 63;
    const int l15 = l & 15;
    const int g   = l >> 4;
    const int w   = tid >> 6;
    const int wm  = w / WC;
    const int wn  = w % WC;

    f32x4 acc[2][MF][NF];
    #pragma unroll
    for (int a2 = 0; a2 < 2; ++a2)
        #pragma unroll
        for (int mf = 0; mf < MF; ++mf)
            #pragma unroll
            for (int nf = 0; nf < NF; ++nf)
                acc[a2][mf][nf] = (f32x4){0.f, 0.f, 0.f, 0.f};

    float xv = 0.f;
    int ta = 0, trow = 0;
    if (TANH) {
        ta = tid >> 7; trow = tid & 127;
        xv = x[(size_t)(b0 + trow) * 256 + 2 * i + ta];
    }

    auto stage = [&](int buf, int k0) {
        if constexpr (TANH) {
            const float* wrow = &Win[(size_t)(2 * i + ta) * 256 + k0];
            char* base = &sA[ta][buf][trow * 64];
            const int sr = (trow >> 1) & 3;
            #pragma unroll
            for (int c = 0; c < 4; ++c) {
                const float4 w0 = *(const float4*)&wrow[c * 8];
                const float4 w1 = *(const float4*)&wrow[c * 8 + 4];
                short8 v;
                v[0] = (short)f2bf(tanh_fast(xv * w0.x));
                v[1] = (short)f2bf(tanh_fast(xv * w0.y));
                v[2] = (short)f2bf(tanh_fast(xv * w0.z));
                v[3] = (short)f2bf(tanh_fast(xv * w0.w));
                v[4] = (short)f2bf(tanh_fast(xv * w1.x));
                v[5] = (short)f2bf(tanh_fast(xv * w1.y));
                v[6] = (short)f2bf(tanh_fast(xv * w1.z));
                v[7] = (short)f2bf(tanh_fast(xv * w1.w));
                *(short8*)(base + ((c ^ sr) << 4)) = v;
            }
        } else {
            #pragma unroll
            for (int uu = 0; uu < UITER; ++uu) {
                const int u = w + uu * 4;
                if (u < AUNITS) {
                    const int ua  = u / (BM / 16);
                    const int r16 = (u % (BM / 16)) * 16;
                    const int row = r16 + (l >> 2);
                    const int c   = l & 3;
                    const ushort* src = H
                        + ((size_t)(b0 + row) * np + (2 * i + ua)) * 256
                        + k0 + ((c ^ ((row >> 1) & 3)) << 3);
                    gll16(src, &sA[ua][buf][r16 * 64]);
                }
            }
        }
        #pragma unroll
        for (int vv = 0; vv < 2; ++vv) {
            const int v    = w + vv * 4;
            const int ea   = v >> 2;
            const int jr16 = (v & 3) * 16;
            const int jr   = jr16 + (l >> 2);
            const int c    = l & 3;
            const ushort* src = E + ((size_t)(2 * i + ea) << 16)
                + (size_t)(j0 + jr) * 256
                + k0 + ((c ^ ((jr >> 1) & 3)) << 3);
            gll16(src, &sB[ea][buf][jr16 * 64]);
        }
    };

    stage(0, 0);
    __syncthreads();

    for (int t = 0; t < 8; ++t) {
        const int buf = t & 1;
        if (t < 7) stage(buf ^ 1, (t + 1) * 32);

        short8 afr[2][MF];
        short8 bfr[2][NF];
        #pragma unroll
        for (int a2 = 0; a2 < 2; ++a2) {
            #pragma unroll
            for (int nf = 0; nf < NF; ++nf) {
                const int jr = wn * (NF * 16) + nf * 16 + l15;
                bfr[a2][nf] = *(const short8*)&sB[a2][buf][jr * 64 + ((g ^ ((jr >> 1) & 3)) << 4)];
            }
            #pragma unroll
            for (int mf = 0; mf < MF; ++mf) {
                const int row = wm * (MF * 16) + mf * 16 + l15;
                afr[a2][mf] = *(const short8*)&sA[a2][buf][row * 64 + ((g ^ ((row >> 1) & 3)) << 4)];
            }
        }
        #pragma unroll
        for (int a2 = 0; a2 < 2; ++a2)
            #pragma unroll
            for (int mf = 0; mf < MF; ++mf)
                #pragma unroll
                for (int nf = 0; nf < NF; ++nf)
                    acc[a2][mf][nf] = __builtin_amdgcn_mfma_f32_16x16x32_bf16(
                        afr[a2][mf], bfr[a2][nf], acc[a2][mf][nf], 0, 0, 0);
        __syncthreads();
    }

    float rc[2][NF];
    #pragma unroll
    for (int a2 = 0; a2 < 2; ++a2)
        #pragma unroll
        for (int nf = 0; nf < NF; ++nf)
            rc[a2][nf] = Rcp[(size_t)(2 * i + a2) * 256 + j0 + wn * (NF * 16) + nf * 16 + l15];

    #pragma unroll
    for (int mf = 0; mf < MF; ++mf)
        #pragma unroll
        for (int nf = 0; nf < NF; ++nf) {
            const int j = j0 + wn * (NF * 16) + nf * 16 + l15;
            #pragma unroll
            for (int r = 0; r < 4; ++r) {
                const int b = b0 + wm * (MF * 16) + mf * 16 + g * 4 + r;
                const float v0 = acc[0][mf][nf][r] * rc[0][nf];
                const float v1 = acc[1][mf][nf][r] * rc[1][nf];
                Hout[((size_t)b * n + i) * 256 + j] = f2bf(v0 * v1);
            }
        }
}

// ---------------------------------------------------------------------------
// Head
// ---------------------------------------------------------------------------
__global__ __launch_bounds__(256)
void out_kernel(const ushort* __restrict__ root, const float* __restrict__ Wout,
                float* __restrict__ out)
{
    __shared__ float sR[16][260];
    __shared__ float sE2[256][12];
    __shared__ float sDen[16];
    const int tid = threadIdx.x;
    if (tid < 16) sDen[tid] = 0.f;
    __syncthreads();
    float e[NCLS];
    #pragma unroll
    for (int c = 0; c < NCLS; ++c) {
        e[c] = __expf(Wout[(size_t)tid * NCLS + c]);
        sE2[tid][c] = e[c];
    }
    #pragma unroll
    for (int c = 0; c < NCLS; ++c) {
        float v = e[c];
        for (int off = 32; off > 0; off >>= 1) v += __shfl_down(v, off);
        if ((tid & 63) == 0) atomicAdd(&sDen[c], v);
    }
    const int b0 = blockIdx.x * 16;
    #pragma unroll
    for (int v = 0; v < 4; ++v) {
        const int u = v * 256 + tid;
        const int row = u >> 6;
        const int c4 = (u & 63) * 4;
        const ushort4 p = *(const ushort4*)&root[(size_t)(b0 + row) * 256 + c4];
        sR[row][c4 + 0] = bf2f(p.x);
        sR[row][c4 + 1] = bf2f(p.y);
        sR[row][c4 + 2] = bf2f(p.z);
        sR[row][c4 + 3] = bf2f(p.w);
    }
    __syncthreads();
    const int ty = tid >> 4, tx = tid & 15;
    if (tx < NCLS) {
        float s = 0.f;
        for (int k = 0; k < 256; ++k) s += sR[ty][k] * sE2[k][tx];
        out[(size_t)(b0 + ty) * NCLS + tx] = s / sDen[tx];
    }
}

extern "C" void kernel_launch(void* const* d_in, const int* in_sizes, int n_in,
                              void* d_out, int out_size, void* d_ws, size_t ws_size,
                              hipStream_t stream)
{
    const float* x    = (const float*)d_in[0];
    const float* Win  = (const float*)d_in[1];
    const float* Wl[8];
    for (int lv = 0; lv < 8; ++lv) Wl[lv] = (const float*)d_in[2 + lv];
    const float* Wout = (const float*)d_in[10];
    float* out = (float*)d_out;

    char* wsb = (char*)d_ws;
    // E offsets (in 64Ki-ushort matrices) for levels 1..7 within the E region
    static const size_t ecum[8] = {0, 0, 128, 192, 224, 240, 248, 252};

    if (ws_size >= 84408320ull) {
        // Main layout: A [0,32Mi): E0 then H2/H4/H6/root (A1 = +16Mi: H3/H5/H7)
        //              C [32Mi,48Mi): H1
        //              B [48Mi,80Mi): H0 then E1..E7
        //              RC [80Mi, +522240)
        ushort* A0 = (ushort*)wsb;
        ushort* A1 = (ushort*)(wsb + 16777216);
        ushort* C  = (ushort*)(wsb + 33554432);
        ushort* B  = (ushort*)(wsb + 50331648);
        float*  RC = (float*)(wsb + 83886080);

        prep1_kernel<<<dim3(1280), 256, 0, stream>>>(Wl[0], x, Win, A0, RC, B);
        level_kernel<128, 2, 2, 3, false><<<dim3(8 * 128), 256, 0, stream>>>(
            nullptr, nullptr, B, A0, RC, C, 128, 7);
        prep2_kernel<<<dim3(1016), 256, 0, stream>>>(
            Wl[1], Wl[2], Wl[3], Wl[4], Wl[5], Wl[6], Wl[7], B, RC);

        level_kernel<64, 2, 2, 4, false><<<dim3(16 * 64), 256, 0, stream>>>(
            nullptr, nullptr, C, B + (ecum[1] << 16), RC + (256 + ecum[1]) * 256, A0, 64, 6);
        level_kernel<64, 2, 2, 4, false><<<dim3(16 * 32), 256, 0, stream>>>(
            nullptr, nullptr, A0, B + (ecum[2] << 16), RC + (256 + ecum[2]) * 256, A1, 32, 5);
        level_kernel<32, 2, 2, 4, false><<<dim3(32 * 16), 256, 0, stream>>>(
            nullptr, nullptr, A1, B + (ecum[3] << 16), RC + (256 + ecum[3]) * 256, A0, 16, 4);
        level_kernel<32, 2, 2, 4, false><<<dim3(32 * 8), 256, 0, stream>>>(
            nullptr, nullptr, A0, B + (ecum[4] << 16), RC + (256 + ecum[4]) * 256, A1, 8, 3);
        level_kernel<16, 1, 4, 4, false><<<dim3(64 * 4), 256, 0, stream>>>(
            nullptr, nullptr, A1, B + (ecum[5] << 16), RC + (256 + ecum[5]) * 256, A0, 4, 2);
        level_kernel<16, 1, 4, 4, false><<<dim3(64 * 2), 256, 0, stream>>>(
            nullptr, nullptr, A0, B + (ecum[6] << 16), RC + (256 + ecum[6]) * 256, A1, 2, 1);
        level_kernel<16, 1, 4, 4, false><<<dim3(64 * 1), 256, 0, stream>>>(
            nullptr, nullptr, A1, B + (ecum[7] << 16), RC + (256 + ecum[7]) * 256, A0, 1, 0);
        out_kernel<<<dim3(16), 256, 0, stream>>>(A0, Wout, out);
    } else {
        // Fallback (proven 56.5Mi layout): tanh stays inside L0
        ushort* R1 = (ushort*)wsb;                    // E0 then E1..E7
        ushort* R2 = (ushort*)(wsb + 33554432);       // H1/H3/H5/H7
        ushort* R3 = (ushort*)(wsb + 50331648);       // H2/H4/H6/root
        float*  RC = (float*)(wsb + 58720256);

        exp0_kernel<<<dim3(4, 256), 256, 0, stream>>>(Wl[0], R1, RC);
        level_kernel<128, 2, 2, 3, true><<<dim3(8 * 128), 256, 0, stream>>>(
            x, Win, nullptr, R1, RC, R2, 128, 7);
        prep2_kernel<<<dim3(1016), 256, 0, stream>>>(
            Wl[1], Wl[2], Wl[3], Wl[4], Wl[5], Wl[6], Wl[7], R1, RC);

        level_kernel<64, 2, 2, 4, false><<<dim3(16 * 64), 256, 0, stream>>>(
            nullptr, nullptr, R2, R1 + (ecum[1] << 16), RC + (256 + ecum[1]) * 256, R3, 64, 6);
        level_kernel<64, 2, 2, 4, false><<<dim3(16 * 32), 256, 0, stream>>>(
            nullptr, nullptr, R3, R1 + (ecum[2] << 16), RC + (256 + ecum[2]) * 256, R2, 32, 5);
        level_kernel<32, 2, 2, 4, false><<<dim3(32 * 16), 256, 0, stream>>>(
            nullptr, nullptr, R2, R1 + (ecum[3] << 16), RC + (256 + ecum[3]) * 256, R3, 16, 4);
        level_kernel<32, 2, 2, 4, false><<<dim3(32 * 8), 256, 0, stream>>>(
            nullptr, nullptr, R3, R1 + (ecum[4] << 16), RC + (256 + ecum[4]) * 256, R2, 8, 3);
        level_kernel<16, 1, 4, 4, false><<<dim3(64 * 4), 256, 0, stream>>>(
            nullptr, nullptr, R2, R1 + (ecum[5] << 16), RC + (256 + ecum[5]) * 256, R3, 4, 2);
        level_kernel<16, 1, 4, 4, false><<<dim3(64 * 2), 256, 0, stream>>>(
            nullptr, nullptr, R3, R1 + (ecum[6] << 16), RC + (256 + ecum[6]) * 256, R2, 2, 1);
        level_kernel<16, 1, 4, 4, false><<<dim3(64 * 1), 256, 0, stream>>>(
            nullptr, nullptr, R2, R1 + (ecum[7] << 16), RC + (256 + ecum[7]) * 256, R3, 1, 0);
        out_kernel<<<dim3(16), 256, 0, stream>>>(R3, Wout, out);
    }
}